// Round 7
// baseline (242.622 us; speedup 1.0000x reference)
//
#include <hip/hip_runtime.h>
#include <math.h>

#define N_ROWS 131072
#define DIM 64
#define KCODES 512

// float-element offsets into d_out (concatenated outputs, all read back as f32)
#define O_LOSS 0
#define O_Q    1ull
#define O_PERP 8388609ull
#define O_ENC  8388610ull
#define O_IDX  75497474ull

// enc region alignment: O_ENC % 4 == 2 -> 2 lead scalars, aligned f4 body, 2 tail scalars
#define ENC_F4_BASE 8388612ull
#define ENC_F4_CNT  16777215ull

// flip-possible window: ref-side grid/rounding <= ~3.1e-5 per pair, our MFMA-path
// delta <= ~2.2e-5 => true bound ~5.3e-5. 1.5e-4 gives 2.8x safety (~3.5K rows).
#define AMB_WIN 1.5e-4f
#define AMB_CAP 32768

using sh8   = __attribute__((ext_vector_type(8))) short;
using f32x4 = __attribute__((ext_vector_type(4))) float;

__device__ __forceinline__ unsigned bf16rne_bits(float x) {
    unsigned u = __float_as_uint(x);
    return u + 0x7fffu + ((u >> 16) & 1u);
}
__device__ __forceinline__ void bf16split(float v, unsigned short& h, unsigned short& s) {
    unsigned hb = bf16rne_bits(v);
    float hf = __uint_as_float(hb & 0xffff0000u);
    unsigned lb = bf16rne_bits(v - hf);
    h = (unsigned short)(hb >> 16);
    s = (unsigned short)(lb >> 16);
}

// ---------------- K0: dense zero of the one-hot region (fillBuffer-style) + accum zeroing ----------------
__global__ __launch_bounds__(256) void vq_zero(float* __restrict__ out, int* __restrict__ counts,
                                               double* __restrict__ loss_acc, int* __restrict__ amb_count) {
    size_t tid = (size_t)blockIdx.x * 256 + threadIdx.x;
    float4 z = make_float4(0.f, 0.f, 0.f, 0.f);
    float4* base = reinterpret_cast<float4*>(out + ENC_F4_BASE);
    size_t stride = (size_t)gridDim.x * 256;
    for (size_t i = tid; i < ENC_F4_CNT; i += stride) base[i] = z;
    if (tid < KCODES) counts[tid] = 0;
    if (tid == 0) {
        out[O_ENC] = 0.f; out[O_ENC + 1] = 0.f;             // lead scalars
        out[O_ENC + 67108862ull] = 0.f; out[O_ENC + 67108863ull] = 0.f;  // tail scalars
        *loss_acc = 0.0; *amb_count = 0;
    }
}

// ---------------- K1 prep: bsq (exact numpy pairwise) + B-fragment tables ----------------
// B-frag layout (proven r6): Bhi[((CT*2+h)*64 + l)*8 + j] = bf16hi(emb[CT*16+(l&15)][(l>>4)*8+32*h+j])
__global__ void vq_prep(const float* __restrict__ emb, float* __restrict__ bsq,
                        unsigned short* __restrict__ Bhi, unsigned short* __restrict__ Blo) {
#pragma clang fp contract(off)
    int t = blockIdx.x * 256 + threadIdx.x;     // grid 128 -> 0..32767
    if (t < KCODES * DIM) {
        int c = t >> 6, d = t & 63;
        unsigned short h, s;
        bf16split(emb[t], h, s);
        int CT = c >> 4, col = c & 15, hh = d >> 5, j = d & 7, lh = (d >> 3) & 3;
        int addr = ((CT * 2 + hh) * 64 + (lh * 16 + col)) * 8 + j;
        Bhi[addr] = h;
        Blo[addr] = s;
    }
    if (t < KCODES) {
        const float* e = emb + (size_t)t * DIM;
        float r[8];
#pragma unroll
        for (int j = 0; j < 8; ++j) { float v = e[j]; r[j] = v * v; }
#pragma unroll
        for (int i = 8; i < 64; i += 8)
#pragma unroll
            for (int j = 0; j < 8; ++j) { float v = e[i + j]; r[j] = r[j] + v * v; }
        bsq[t] = ((r[0] + r[1]) + (r[2] + r[3])) + ((r[4] + r[5]) + (r[6] + r[7]));
    }
}

// ---------------- K2: MFMA distances, 128 rows/block, 2 row-tiles/wave; writes idx/ones/Q/loss ----------------
__global__ __launch_bounds__(256) void vq_mfma(
    const float* __restrict__ x, const float* __restrict__ emb,
    const float* __restrict__ bsq,
    const unsigned short* __restrict__ Bhi, const unsigned short* __restrict__ Blo,
    int* __restrict__ counts, double* __restrict__ loss_acc, float* __restrict__ out,
    int* __restrict__ amb_count, int* __restrict__ amb_rows)
{
    __shared__ int    idx_l[128];
    __shared__ double wsum[4];

    const int tid  = threadIdx.x;
    const int l    = tid & 63;
    const int w    = tid >> 6;                 // wave 0..3
    const int row0 = blockIdx.x * 128;
    const int kb   = (l >> 4) * 8;             // lane k-offset
    const int rA   = row0 + w * 16 + (l & 15); // tile A row
    const int rB   = rA + 64;                  // tile B row

    // ---- A fragments for two row-tiles: global loads + register bf16 split ----
    sh8 ahf[2][2], alf[2][2];
#pragma unroll
    for (int t = 0; t < 2; ++t) {
        const float* xr = &x[(size_t)(t == 0 ? rA : rB) * 64 + kb];
        float4 a0 = *reinterpret_cast<const float4*>(xr);
        float4 a1 = *reinterpret_cast<const float4*>(xr + 4);
        float4 a2 = *reinterpret_cast<const float4*>(xr + 32);
        float4 a3 = *reinterpret_cast<const float4*>(xr + 36);
        float av[16] = {a0.x,a0.y,a0.z,a0.w, a1.x,a1.y,a1.z,a1.w,
                        a2.x,a2.y,a2.z,a2.w, a3.x,a3.y,a3.z,a3.w};
        unsigned short ah[16], al[16];
#pragma unroll
        for (int i = 0; i < 16; ++i) bf16split(av[i], ah[i], al[i]);
        ahf[t][0] = *reinterpret_cast<sh8*>(&ah[0]);
        ahf[t][1] = *reinterpret_cast<sh8*>(&ah[8]);
        alf[t][0] = *reinterpret_cast<sh8*>(&al[0]);
        alf[t][1] = *reinterpret_cast<sh8*>(&al[8]);
    }

    float m1[2][4], m2[2][4];
    int   i1[2][4];
#pragma unroll
    for (int t = 0; t < 2; ++t)
#pragma unroll
        for (int j = 0; j < 4; ++j) { m1[t][j] = 3.4e38f; m2[t][j] = 3.4e38f; i1[t][j] = 0; }

    const int col = l & 15;
#pragma unroll 2
    for (int CT = 0; CT < 32; ++CT) {
        sh8 bh0 = *reinterpret_cast<const sh8*>(&Bhi[(size_t)(CT * 2 + 0) * 512 + l * 8]);
        sh8 bh1 = *reinterpret_cast<const sh8*>(&Bhi[(size_t)(CT * 2 + 1) * 512 + l * 8]);
        sh8 bl0 = *reinterpret_cast<const sh8*>(&Blo[(size_t)(CT * 2 + 0) * 512 + l * 8]);
        sh8 bl1 = *reinterpret_cast<const sh8*>(&Blo[(size_t)(CT * 2 + 1) * 512 + l * 8]);
        int code = CT * 16 + col;
        float bs = bsq[code];
#pragma unroll
        for (int t = 0; t < 2; ++t) {
            f32x4 acc = {0.f, 0.f, 0.f, 0.f};
            acc = __builtin_amdgcn_mfma_f32_16x16x32_bf16(ahf[t][0], bh0, acc, 0, 0, 0);
            acc = __builtin_amdgcn_mfma_f32_16x16x32_bf16(ahf[t][1], bh1, acc, 0, 0, 0);
            acc = __builtin_amdgcn_mfma_f32_16x16x32_bf16(ahf[t][0], bl0, acc, 0, 0, 0);
            acc = __builtin_amdgcn_mfma_f32_16x16x32_bf16(ahf[t][1], bl1, acc, 0, 0, 0);
            acc = __builtin_amdgcn_mfma_f32_16x16x32_bf16(alf[t][0], bh0, acc, 0, 0, 0);
            acc = __builtin_amdgcn_mfma_f32_16x16x32_bf16(alf[t][1], bh1, acc, 0, 0, 0);
#pragma unroll
            for (int j = 0; j < 4; ++j) {
                float tt = bs - 2.0f * acc[j];     // ||x||^2 dropped: uniform per-row shift
                if (tt < m1[t][j]) { m2[t][j] = m1[t][j]; m1[t][j] = tt; i1[t][j] = code; }
                else if (tt < m2[t][j]) { m2[t][j] = tt; }
            }
        }
    }

    // ---- reduce (min, argmin, 2nd-min) across the 16 lanes sharing (l>>4) ----
#pragma unroll
    for (int off = 8; off >= 1; off >>= 1)
#pragma unroll
        for (int t = 0; t < 2; ++t)
#pragma unroll
            for (int j = 0; j < 4; ++j) {
                float ov1 = __shfl_xor(m1[t][j], off, 64);
                int   oi1 = __shfl_xor(i1[t][j], off, 64);
                float ov2 = __shfl_xor(m2[t][j], off, 64);
                float hi  = fmaxf(m1[t][j], ov1);
                m2[t][j] = fminf(fminf(m2[t][j], ov2), hi);
                if (ov1 < m1[t][j] || (ov1 == m1[t][j] && oi1 < i1[t][j])) { m1[t][j] = ov1; i1[t][j] = oi1; }
            }

    if ((l & 15) == 0) {
#pragma unroll
        for (int t = 0; t < 2; ++t)
#pragma unroll
            for (int j = 0; j < 4; ++j) {
                int r_loc = t * 64 + w * 16 + ((l >> 4) << 2) + j;   // D row = (lane>>4)*4 + reg
                int id = i1[t][j];
                idx_l[r_loc] = id;
                out[O_IDX + row0 + r_loc] = (float)id;
                out[O_ENC + (size_t)(row0 + r_loc) * KCODES + id] = 1.0f;  // the single one-hot
                atomicAdd(&counts[id], 1);
                if (m2[t][j] - m1[t][j] <= AMB_WIN) {
                    int slot = atomicAdd(amb_count, 1);
                    if (slot < AMB_CAP) amb_rows[slot] = row0 + r_loc;
                }
            }
    }
    __syncthreads();

    // ---- quantized_st + loss partial (dense scalar stores; x/emb L1-hot) ----
    double lsum = 0.0;
#pragma unroll 4
    for (int k = 0; k < 32; ++k) {
        int i = tid + k * 256;               // 0..8191
        int r = i >> 6, d = i & 63;
        int id = idx_l[r];
        float xv = x[(size_t)(row0 + r) * 64 + d];
        float ev = emb[(size_t)id * 64 + d];
        float diff = ev - xv;
        out[O_Q + (size_t)(row0 + r) * 64 + d] = xv + diff;
        lsum += (double)diff * (double)diff;
    }

#pragma unroll
    for (int off = 32; off >= 1; off >>= 1) lsum += __shfl_xor(lsum, off, 64);
    if ((tid & 63) == 0) wsum[tid >> 6] = lsum;
    __syncthreads();
    if (tid == 0) atomicAdd(loss_acc, wsum[0] + wsum[1] + wsum[2] + wsum[3]);
}

// ---------------- K3: bit-exact np-replica recompute for ambiguous rows ----------------
__global__ __launch_bounds__(256, 2) void vq_fixup(
    const float* __restrict__ x, const float* __restrict__ emb,
    const float* __restrict__ bsq, int* __restrict__ counts,
    double* __restrict__ loss_acc, float* __restrict__ out,
    const int* __restrict__ amb_count, const int* __restrict__ amb_rows)
{
#pragma clang fp contract(off)
    __shared__ float Xt[64 * 34];     // Xt[d*34 + r], 32 rows
    __shared__ float Et[64 * 68];     // Et[d*68 + c], 64 codes/chunk
    __shared__ float sx_l[32];
    __shared__ int   rowid_l[32];

    const int tid = threadIdx.x;
    const int tx  = tid & 15;         // 4 codes each
    const int ty  = tid >> 4;         // 2 rows each
    int n = *amb_count; if (n > AMB_CAP) n = AMB_CAP;

    for (int base = blockIdx.x * 32; base < n; base += gridDim.x * 32) {
        const int nrows = min(32, n - base);
        if (tid < 32) {
            int e = base + tid;
            rowid_l[tid] = amb_rows[e < n ? e : (n - 1)];
        }
        __syncthreads();

#pragma unroll
        for (int k = 0; k < 8; ++k) {
            int i = tid + k * 256;    // 0..2047
            int r = i >> 6, d = i & 63;
            Xt[d * 34 + r] = x[(size_t)rowid_l[r] * 64 + d];
        }
        __syncthreads();

        if (tid < 32) {
            float rr[8];
#pragma unroll
            for (int j = 0; j < 8; ++j) { float v = Xt[j * 34 + tid]; rr[j] = v * v; }
#pragma unroll
            for (int i = 8; i < 64; i += 8)
#pragma unroll
                for (int j = 0; j < 8; ++j) { float v = Xt[(i + j) * 34 + tid]; rr[j] = rr[j] + v * v; }
            sx_l[tid] = ((rr[0] + rr[1]) + (rr[2] + rr[3])) + ((rr[4] + rr[5]) + (rr[6] + rr[7]));
        }
        __syncthreads();

        float b1[2]; int bi[2];
#pragma unroll
        for (int m = 0; m < 2; ++m) { b1[m] = 3.4e38f; bi[m] = 0; }

        for (int ch = 0; ch < 8; ++ch) {
            if (ch > 0) __syncthreads();
#pragma unroll
            for (int k = 0; k < 4; ++k) {
                int i = tid + k * 256;        // 0..1023 float4-units
                int c = i >> 4, c4 = i & 15;
                float4 v = *reinterpret_cast<const float4*>(&emb[(size_t)(ch * 64 + c) * 64 + c4 * 4]);
                Et[(c4 * 4 + 0) * 68 + c] = v.x;
                Et[(c4 * 4 + 1) * 68 + c] = v.y;
                Et[(c4 * 4 + 2) * 68 + c] = v.z;
                Et[(c4 * 4 + 3) * 68 + c] = v.w;
            }
            __syncthreads();

            float acc[2][4];
#pragma unroll
            for (int m = 0; m < 2; ++m)
#pragma unroll
                for (int nn = 0; nn < 4; ++nn) acc[m][nn] = 0.f;

#pragma unroll 8
            for (int d = 0; d < 64; ++d) {
                float2 a = *reinterpret_cast<const float2*>(&Xt[d * 34 + ty * 2]);
                float4 b = *reinterpret_cast<const float4*>(&Et[d * 68 + tx * 4]);
                float av[2] = {a.x, a.y};
                float bv[4] = {b.x, b.y, b.z, b.w};
#pragma unroll
                for (int m = 0; m < 2; ++m)
#pragma unroll
                    for (int nn = 0; nn < 4; ++nn)
                        acc[m][nn] = fmaf(av[m], bv[nn], acc[m][nn]);
            }

            const int cbase = ch * 64 + tx * 4;
            float4 bs4 = *reinterpret_cast<const float4*>(&bsq[cbase]);
            float bs[4] = {bs4.x, bs4.y, bs4.z, bs4.w};
#pragma unroll
            for (int m = 0; m < 2; ++m) {
                float sxm = sx_l[ty * 2 + m];
#pragma unroll
                for (int nn = 0; nn < 4; ++nn) {
                    float S  = sxm + bs[nn];
                    float dd = S - 2.0f * acc[m][nn];   // exact ref rounding
                    if (dd < b1[m]) { b1[m] = dd; bi[m] = cbase + nn; }
                }
            }
        }

#pragma unroll
        for (int off = 8; off >= 1; off >>= 1)
#pragma unroll
            for (int m = 0; m < 2; ++m) {
                float ov = __shfl_xor(b1[m], off, 64);
                int   oi = __shfl_xor(bi[m], off, 64);
                if (ov < b1[m] || (ov == b1[m] && oi < bi[m])) { b1[m] = ov; bi[m] = oi; }
            }

        if (tx == 0) {
#pragma unroll
            for (int m = 0; m < 2; ++m) {
                int rl = ty * 2 + m;
                if (rl < nrows) {
                    int row = rowid_l[rl];
                    int fi  = bi[m];
                    int old = (int)out[O_IDX + row];
                    if (fi != old) {
                        out[O_IDX + row] = (float)fi;
                        out[O_ENC + (size_t)row * KCODES + old] = 0.f;
                        out[O_ENC + (size_t)row * KCODES + fi]  = 1.f;
                        atomicAdd(&counts[old], -1);
                        atomicAdd(&counts[fi], 1);
                        double dl = 0.0;
                        for (int d = 0; d < 64; ++d) {
                            float xv   = Xt[d * 34 + rl];
                            float dn   = emb[(size_t)fi * 64 + d] - xv;
                            float dold = emb[(size_t)old * 64 + d] - xv;
                            out[O_Q + (size_t)row * 64 + d] = xv + dn;
                            dl += (double)dn * (double)dn - (double)dold * (double)dold;
                        }
                        atomicAdd(loss_acc, dl);
                    }
                }
            }
        }
        __syncthreads();
    }
}

// ---------------- K4 finalize: scalars ----------------
__global__ void vq_fin(const int* __restrict__ counts, const double* __restrict__ loss_acc,
                       float* __restrict__ out) {
    int t = threadIdx.x;     // 256
    double h = 0.0;
    for (int c = t; c < KCODES; c += 256) {
        double p = (double)counts[c] / (double)N_ROWS;
        h += p * log(p + 1e-10);
    }
#pragma unroll
    for (int off = 32; off >= 1; off >>= 1) h += __shfl_xor(h, off, 64);
    __shared__ double ws[4];
    if ((t & 63) == 0) ws[t >> 6] = h;
    __syncthreads();
    if (t == 0) {
        double H = ws[0] + ws[1] + ws[2] + ws[3];
        out[O_PERP] = (float)exp(-H);
        out[O_LOSS] = (float)(1.25 * (*loss_acc) / (double)(N_ROWS * DIM));
    }
}

extern "C" void kernel_launch(void* const* d_in, const int* in_sizes, int n_in,
                              void* d_out, int out_size, void* d_ws, size_t ws_size,
                              hipStream_t stream) {
    const float* x   = (const float*)d_in[0];
    const float* emb = (const float*)d_in[1];
    float* out = (float*)d_out;

    // ws: [0,2048) f32 bsq | [2048,4096) int counts | 4096 f64 loss | 4112 amb_count |
    //     [4160, 4160+4*AMB_CAP) amb_rows | 139264 Bhi (64KB) | 212992 Blo (64KB)
    float*          bsq       = (float*)d_ws;
    int*            counts    = (int*)((char*)d_ws + 2048);
    double*         loss_acc  = (double*)((char*)d_ws + 4096);
    int*            amb_count = (int*)((char*)d_ws + 4112);
    int*            amb_rows  = (int*)((char*)d_ws + 4160);
    unsigned short* Bhi       = (unsigned short*)((char*)d_ws + 139264);
    unsigned short* Blo       = (unsigned short*)((char*)d_ws + 212992);

    vq_zero<<<2048, 256, 0, stream>>>(out, counts, loss_acc, amb_count);
    vq_prep<<<128, 256, 0, stream>>>(emb, bsq, Bhi, Blo);
    vq_mfma<<<N_ROWS / 128, 256, 0, stream>>>(x, emb, bsq, Bhi, Blo, counts, loss_acc, out,
                                              amb_count, amb_rows);
    vq_fixup<<<1024, 256, 0, stream>>>(x, emb, bsq, counts, loss_acc, out,
                                       amb_count, amb_rows);
    vq_fin<<<1, 256, 0, stream>>>(counts, loss_acc, out);
}

// Round 8
// 241.422 us; speedup vs baseline: 1.0050x; 1.0050x over previous
//
#include <hip/hip_runtime.h>
#include <math.h>

#define N_ROWS 131072
#define DIM 64
#define KCODES 512

// float-element offsets into d_out (concatenated outputs, all read back as f32)
#define O_LOSS 0
#define O_Q    1ull
#define O_PERP 8388609ull
#define O_ENC  8388610ull
#define O_IDX  75497474ull

// enc region in BYTES for memset: [O_ENC*4, O_ENC*4 + 67108864*4)
#define ENC_BYTE_OFF 33554440ull
#define ENC_BYTE_LEN 268435456ull

// flip-possible window: ref-side grid/rounding <= ~3.1e-5 per pair, our MFMA-path
// delta <= ~2.2e-5 => true bound ~5.3e-5. 1.5e-4 gives 2.8x safety (~3.5K rows).
#define AMB_WIN 1.5e-4f
#define AMB_CAP 32768

using sh8   = __attribute__((ext_vector_type(8))) short;
using f32x4 = __attribute__((ext_vector_type(4))) float;

__device__ __forceinline__ unsigned bf16rne_bits(float x) {
    unsigned u = __float_as_uint(x);
    return u + 0x7fffu + ((u >> 16) & 1u);
}
__device__ __forceinline__ void bf16split(float v, unsigned short& h, unsigned short& s) {
    unsigned hb = bf16rne_bits(v);
    float hf = __uint_as_float(hb & 0xffff0000u);
    unsigned lb = bf16rne_bits(v - hf);
    h = (unsigned short)(hb >> 16);
    s = (unsigned short)(lb >> 16);
}

// ---------------- K1 prep: bsq (exact numpy pairwise) + B-fragment tables ----------------
// B-frag layout (proven r6): Bhi[((CT*2+h)*64 + l)*8 + j] = bf16hi(emb[CT*16+(l&15)][(l>>4)*8+32*h+j])
__global__ void vq_prep(const float* __restrict__ emb, float* __restrict__ bsq,
                        unsigned short* __restrict__ Bhi, unsigned short* __restrict__ Blo) {
#pragma clang fp contract(off)
    int t = blockIdx.x * 256 + threadIdx.x;     // grid 128 -> 0..32767
    if (t < KCODES * DIM) {
        int c = t >> 6, d = t & 63;
        unsigned short h, s;
        bf16split(emb[t], h, s);
        int CT = c >> 4, col = c & 15, hh = d >> 5, j = d & 7, lh = (d >> 3) & 3;
        int addr = ((CT * 2 + hh) * 64 + (lh * 16 + col)) * 8 + j;
        Bhi[addr] = h;
        Blo[addr] = s;
    }
    if (t < KCODES) {
        const float* e = emb + (size_t)t * DIM;
        float r[8];
#pragma unroll
        for (int j = 0; j < 8; ++j) { float v = e[j]; r[j] = v * v; }
#pragma unroll
        for (int i = 8; i < 64; i += 8)
#pragma unroll
            for (int j = 0; j < 8; ++j) { float v = e[i + j]; r[j] = r[j] + v * v; }
        bsq[t] = ((r[0] + r[1]) + (r[2] + r[3])) + ((r[4] + r[5]) + (r[6] + r[7]));
    }
}

// ---------------- K2: MFMA distances, 128 rows/block, 2 row-tiles/wave; writes idx/ones/Q/loss ----------------
__global__ __launch_bounds__(256) void vq_mfma(
    const float* __restrict__ x, const float* __restrict__ emb,
    const float* __restrict__ bsq,
    const unsigned short* __restrict__ Bhi, const unsigned short* __restrict__ Blo,
    int* __restrict__ counts, double* __restrict__ loss_acc, float* __restrict__ out,
    int* __restrict__ amb_count, int* __restrict__ amb_rows)
{
    __shared__ int    idx_l[128];
    __shared__ double wsum[4];

    const int tid  = threadIdx.x;
    const int l    = tid & 63;
    const int w    = tid >> 6;                 // wave 0..3
    const int row0 = blockIdx.x * 128;
    const int kb   = (l >> 4) * 8;             // lane k-offset
    const int rA   = row0 + w * 16 + (l & 15); // tile A row
    const int rB   = rA + 64;                  // tile B row

    // ---- A fragments for two row-tiles: global loads + register bf16 split ----
    sh8 ahf[2][2], alf[2][2];
#pragma unroll
    for (int t = 0; t < 2; ++t) {
        const float* xr = &x[(size_t)(t == 0 ? rA : rB) * 64 + kb];
        float4 a0 = *reinterpret_cast<const float4*>(xr);
        float4 a1 = *reinterpret_cast<const float4*>(xr + 4);
        float4 a2 = *reinterpret_cast<const float4*>(xr + 32);
        float4 a3 = *reinterpret_cast<const float4*>(xr + 36);
        float av[16] = {a0.x,a0.y,a0.z,a0.w, a1.x,a1.y,a1.z,a1.w,
                        a2.x,a2.y,a2.z,a2.w, a3.x,a3.y,a3.z,a3.w};
        unsigned short ah[16], al[16];
#pragma unroll
        for (int i = 0; i < 16; ++i) bf16split(av[i], ah[i], al[i]);
        ahf[t][0] = *reinterpret_cast<sh8*>(&ah[0]);
        ahf[t][1] = *reinterpret_cast<sh8*>(&ah[8]);
        alf[t][0] = *reinterpret_cast<sh8*>(&al[0]);
        alf[t][1] = *reinterpret_cast<sh8*>(&al[8]);
    }

    float m1[2][4], m2[2][4];
    int   i1[2][4];
#pragma unroll
    for (int t = 0; t < 2; ++t)
#pragma unroll
        for (int j = 0; j < 4; ++j) { m1[t][j] = 3.4e38f; m2[t][j] = 3.4e38f; i1[t][j] = 0; }

    const int col = l & 15;
#pragma unroll 2
    for (int CT = 0; CT < 32; ++CT) {
        sh8 bh0 = *reinterpret_cast<const sh8*>(&Bhi[(size_t)(CT * 2 + 0) * 512 + l * 8]);
        sh8 bh1 = *reinterpret_cast<const sh8*>(&Bhi[(size_t)(CT * 2 + 1) * 512 + l * 8]);
        sh8 bl0 = *reinterpret_cast<const sh8*>(&Blo[(size_t)(CT * 2 + 0) * 512 + l * 8]);
        sh8 bl1 = *reinterpret_cast<const sh8*>(&Blo[(size_t)(CT * 2 + 1) * 512 + l * 8]);
        int code = CT * 16 + col;
        float bs = bsq[code];
#pragma unroll
        for (int t = 0; t < 2; ++t) {
            f32x4 acc = {0.f, 0.f, 0.f, 0.f};
            acc = __builtin_amdgcn_mfma_f32_16x16x32_bf16(ahf[t][0], bh0, acc, 0, 0, 0);
            acc = __builtin_amdgcn_mfma_f32_16x16x32_bf16(ahf[t][1], bh1, acc, 0, 0, 0);
            acc = __builtin_amdgcn_mfma_f32_16x16x32_bf16(ahf[t][0], bl0, acc, 0, 0, 0);
            acc = __builtin_amdgcn_mfma_f32_16x16x32_bf16(ahf[t][1], bl1, acc, 0, 0, 0);
            acc = __builtin_amdgcn_mfma_f32_16x16x32_bf16(alf[t][0], bh0, acc, 0, 0, 0);
            acc = __builtin_amdgcn_mfma_f32_16x16x32_bf16(alf[t][1], bh1, acc, 0, 0, 0);
#pragma unroll
            for (int j = 0; j < 4; ++j) {
                float tt = bs - 2.0f * acc[j];     // ||x||^2 dropped: uniform per-row shift
                if (tt < m1[t][j]) { m2[t][j] = m1[t][j]; m1[t][j] = tt; i1[t][j] = code; }
                else if (tt < m2[t][j]) { m2[t][j] = tt; }
            }
        }
    }

    // ---- reduce (min, argmin, 2nd-min) across the 16 lanes sharing (l>>4) ----
#pragma unroll
    for (int off = 8; off >= 1; off >>= 1)
#pragma unroll
        for (int t = 0; t < 2; ++t)
#pragma unroll
            for (int j = 0; j < 4; ++j) {
                float ov1 = __shfl_xor(m1[t][j], off, 64);
                int   oi1 = __shfl_xor(i1[t][j], off, 64);
                float ov2 = __shfl_xor(m2[t][j], off, 64);
                float hi  = fmaxf(m1[t][j], ov1);
                m2[t][j] = fminf(fminf(m2[t][j], ov2), hi);
                if (ov1 < m1[t][j] || (ov1 == m1[t][j] && oi1 < i1[t][j])) { m1[t][j] = ov1; i1[t][j] = oi1; }
            }

    if ((l & 15) == 0) {
#pragma unroll
        for (int t = 0; t < 2; ++t)
#pragma unroll
            for (int j = 0; j < 4; ++j) {
                int r_loc = t * 64 + w * 16 + ((l >> 4) << 2) + j;   // D row = (lane>>4)*4 + reg
                int id = i1[t][j];
                idx_l[r_loc] = id;
                out[O_IDX + row0 + r_loc] = (float)id;
                out[O_ENC + (size_t)(row0 + r_loc) * KCODES + id] = 1.0f;  // the single one-hot
                atomicAdd(&counts[id], 1);
                if (m2[t][j] - m1[t][j] <= AMB_WIN) {
                    int slot = atomicAdd(amb_count, 1);
                    if (slot < AMB_CAP) amb_rows[slot] = row0 + r_loc;
                }
            }
    }
    __syncthreads();

    // ---- quantized_st + loss partial (dense scalar stores; x/emb L1-hot) ----
    double lsum = 0.0;
#pragma unroll 4
    for (int k = 0; k < 32; ++k) {
        int i = tid + k * 256;               // 0..8191
        int r = i >> 6, d = i & 63;
        int id = idx_l[r];
        float xv = x[(size_t)(row0 + r) * 64 + d];
        float ev = emb[(size_t)id * 64 + d];
        float diff = ev - xv;
        out[O_Q + (size_t)(row0 + r) * 64 + d] = xv + diff;
        lsum += (double)diff * (double)diff;
    }

#pragma unroll
    for (int off = 32; off >= 1; off >>= 1) lsum += __shfl_xor(lsum, off, 64);
    if ((tid & 63) == 0) wsum[tid >> 6] = lsum;
    __syncthreads();
    if (tid == 0) atomicAdd(loss_acc, wsum[0] + wsum[1] + wsum[2] + wsum[3]);
}

// ---------------- K3: bit-exact np-replica recompute for ambiguous rows ----------------
__global__ __launch_bounds__(256, 2) void vq_fixup(
    const float* __restrict__ x, const float* __restrict__ emb,
    const float* __restrict__ bsq, int* __restrict__ counts,
    double* __restrict__ loss_acc, float* __restrict__ out,
    const int* __restrict__ amb_count, const int* __restrict__ amb_rows)
{
#pragma clang fp contract(off)
    __shared__ float Xt[64 * 34];     // Xt[d*34 + r], 32 rows
    __shared__ float Et[64 * 68];     // Et[d*68 + c], 64 codes/chunk
    __shared__ float sx_l[32];
    __shared__ int   rowid_l[32];

    const int tid = threadIdx.x;
    const int tx  = tid & 15;         // 4 codes each
    const int ty  = tid >> 4;         // 2 rows each
    int n = *amb_count; if (n > AMB_CAP) n = AMB_CAP;

    for (int base = blockIdx.x * 32; base < n; base += gridDim.x * 32) {
        const int nrows = min(32, n - base);
        if (tid < 32) {
            int e = base + tid;
            rowid_l[tid] = amb_rows[e < n ? e : (n - 1)];
        }
        __syncthreads();

#pragma unroll
        for (int k = 0; k < 8; ++k) {
            int i = tid + k * 256;    // 0..2047
            int r = i >> 6, d = i & 63;
            Xt[d * 34 + r] = x[(size_t)rowid_l[r] * 64 + d];
        }
        __syncthreads();

        if (tid < 32) {
            float rr[8];
#pragma unroll
            for (int j = 0; j < 8; ++j) { float v = Xt[j * 34 + tid]; rr[j] = v * v; }
#pragma unroll
            for (int i = 8; i < 64; i += 8)
#pragma unroll
                for (int j = 0; j < 8; ++j) { float v = Xt[(i + j) * 34 + tid]; rr[j] = rr[j] + v * v; }
            sx_l[tid] = ((rr[0] + rr[1]) + (rr[2] + rr[3])) + ((rr[4] + rr[5]) + (rr[6] + rr[7]));
        }
        __syncthreads();

        float b1[2]; int bi[2];
#pragma unroll
        for (int m = 0; m < 2; ++m) { b1[m] = 3.4e38f; bi[m] = 0; }

        for (int ch = 0; ch < 8; ++ch) {
            if (ch > 0) __syncthreads();
#pragma unroll
            for (int k = 0; k < 4; ++k) {
                int i = tid + k * 256;        // 0..1023 float4-units
                int c = i >> 4, c4 = i & 15;
                float4 v = *reinterpret_cast<const float4*>(&emb[(size_t)(ch * 64 + c) * 64 + c4 * 4]);
                Et[(c4 * 4 + 0) * 68 + c] = v.x;
                Et[(c4 * 4 + 1) * 68 + c] = v.y;
                Et[(c4 * 4 + 2) * 68 + c] = v.z;
                Et[(c4 * 4 + 3) * 68 + c] = v.w;
            }
            __syncthreads();

            float acc[2][4];
#pragma unroll
            for (int m = 0; m < 2; ++m)
#pragma unroll
                for (int nn = 0; nn < 4; ++nn) acc[m][nn] = 0.f;

#pragma unroll 8
            for (int d = 0; d < 64; ++d) {
                float2 a = *reinterpret_cast<const float2*>(&Xt[d * 34 + ty * 2]);
                float4 b = *reinterpret_cast<const float4*>(&Et[d * 68 + tx * 4]);
                float av[2] = {a.x, a.y};
                float bv[4] = {b.x, b.y, b.z, b.w};
#pragma unroll
                for (int m = 0; m < 2; ++m)
#pragma unroll
                    for (int nn = 0; nn < 4; ++nn)
                        acc[m][nn] = fmaf(av[m], bv[nn], acc[m][nn]);
            }

            const int cbase = ch * 64 + tx * 4;
            float4 bs4 = *reinterpret_cast<const float4*>(&bsq[cbase]);
            float bs[4] = {bs4.x, bs4.y, bs4.z, bs4.w};
#pragma unroll
            for (int m = 0; m < 2; ++m) {
                float sxm = sx_l[ty * 2 + m];
#pragma unroll
                for (int nn = 0; nn < 4; ++nn) {
                    float S  = sxm + bs[nn];
                    float dd = S - 2.0f * acc[m][nn];   // exact ref rounding
                    if (dd < b1[m]) { b1[m] = dd; bi[m] = cbase + nn; }
                }
            }
        }

#pragma unroll
        for (int off = 8; off >= 1; off >>= 1)
#pragma unroll
            for (int m = 0; m < 2; ++m) {
                float ov = __shfl_xor(b1[m], off, 64);
                int   oi = __shfl_xor(bi[m], off, 64);
                if (ov < b1[m] || (ov == b1[m] && oi < bi[m])) { b1[m] = ov; bi[m] = oi; }
            }

        if (tx == 0) {
#pragma unroll
            for (int m = 0; m < 2; ++m) {
                int rl = ty * 2 + m;
                if (rl < nrows) {
                    int row = rowid_l[rl];
                    int fi  = bi[m];
                    int old = (int)out[O_IDX + row];
                    if (fi != old) {
                        out[O_IDX + row] = (float)fi;
                        out[O_ENC + (size_t)row * KCODES + old] = 0.f;
                        out[O_ENC + (size_t)row * KCODES + fi]  = 1.f;
                        atomicAdd(&counts[old], -1);
                        atomicAdd(&counts[fi], 1);
                        double dl = 0.0;
                        for (int d = 0; d < 64; ++d) {
                            float xv   = Xt[d * 34 + rl];
                            float dn   = emb[(size_t)fi * 64 + d] - xv;
                            float dold = emb[(size_t)old * 64 + d] - xv;
                            out[O_Q + (size_t)row * 64 + d] = xv + dn;
                            dl += (double)dn * (double)dn - (double)dold * (double)dold;
                        }
                        atomicAdd(loss_acc, dl);
                    }
                }
            }
        }
        __syncthreads();
    }
}

// ---------------- K4 finalize: scalars ----------------
__global__ void vq_fin(const int* __restrict__ counts, const double* __restrict__ loss_acc,
                       float* __restrict__ out) {
    int t = threadIdx.x;     // 256
    double h = 0.0;
    for (int c = t; c < KCODES; c += 256) {
        double p = (double)counts[c] / (double)N_ROWS;
        h += p * log(p + 1e-10);
    }
#pragma unroll
    for (int off = 32; off >= 1; off >>= 1) h += __shfl_xor(h, off, 64);
    __shared__ double ws[4];
    if ((t & 63) == 0) ws[t >> 6] = h;
    __syncthreads();
    if (t == 0) {
        double H = ws[0] + ws[1] + ws[2] + ws[3];
        out[O_PERP] = (float)exp(-H);
        out[O_LOSS] = (float)(1.25 * (*loss_acc) / (double)(N_ROWS * DIM));
    }
}

extern "C" void kernel_launch(void* const* d_in, const int* in_sizes, int n_in,
                              void* d_out, int out_size, void* d_ws, size_t ws_size,
                              hipStream_t stream) {
    const float* x   = (const float*)d_in[0];
    const float* emb = (const float*)d_in[1];
    float* out = (float*)d_out;

    // ws: [0,2048) f32 bsq | [2048,4096) int counts | 4096 f64 loss | 4112 amb_count |
    //     [4160, 4160+4*AMB_CAP) amb_rows | 139264 Bhi (64KB) | 212992 Blo (64KB)
    float*          bsq       = (float*)d_ws;
    int*            counts    = (int*)((char*)d_ws + 2048);
    double*         loss_acc  = (double*)((char*)d_ws + 4096);
    int*            amb_count = (int*)((char*)d_ws + 4112);
    int*            amb_rows  = (int*)((char*)d_ws + 4160);
    unsigned short* Bhi       = (unsigned short*)((char*)d_ws + 139264);
    unsigned short* Blo       = (unsigned short*)((char*)d_ws + 212992);

    // Zero the 268 MB one-hot region via the runtime's fill path (fillBuffer runs
    // at ~6.8 TB/s vs ~1.6 TB/s for our own store loops -- r7 experiment).
    hipMemsetAsync((char*)d_out + ENC_BYTE_OFF, 0, ENC_BYTE_LEN, stream);
    // Zero counts[512] + loss_acc + amb_count in one small memset: bytes [2048, 4128).
    hipMemsetAsync((char*)d_ws + 2048, 0, 2080, stream);

    vq_prep<<<128, 256, 0, stream>>>(emb, bsq, Bhi, Blo);
    vq_mfma<<<N_ROWS / 128, 256, 0, stream>>>(x, emb, bsq, Bhi, Blo, counts, loss_acc, out,
                                              amb_count, amb_rows);
    vq_fixup<<<1024, 256, 0, stream>>>(x, emb, bsq, counts, loss_acc, out,
                                       amb_count, amb_rows);
    vq_fin<<<1, 256, 0, stream>>>(counts, loss_acc, out);
}

// Round 10
// 229.593 us; speedup vs baseline: 1.0567x; 1.0515x over previous
//
#include <hip/hip_runtime.h>
#include <math.h>

#define N_ROWS 131072
#define DIM 64
#define KCODES 512

// float-element offsets into d_out (concatenated outputs, all read back as f32)
#define O_LOSS 0
#define O_Q    1ull
#define O_PERP 8388609ull
#define O_ENC  8388610ull
#define O_IDX  75497474ull

// flip-possible window: ref-side grid/rounding <= ~3.1e-5 per pair, our MFMA-path
// delta <= ~2.2e-5 => true bound ~5.3e-5. 1.5e-4 gives 2.8x safety (~3.5K rows).
#define AMB_WIN 1.5e-4f
#define AMB_CAP 32768

using sh8   = __attribute__((ext_vector_type(8))) short;
using f32x4 = __attribute__((ext_vector_type(4))) float;

__device__ __forceinline__ unsigned bf16rne_bits(float x) {
    unsigned u = __float_as_uint(x);
    return u + 0x7fffu + ((u >> 16) & 1u);
}
__device__ __forceinline__ void bf16split(float v, unsigned short& h, unsigned short& s) {
    unsigned hb = bf16rne_bits(v);
    float hf = __uint_as_float(hb & 0xffff0000u);
    unsigned lb = bf16rne_bits(v - hf);
    h = (unsigned short)(hb >> 16);
    s = (unsigned short)(lb >> 16);
}

// ---------------- K1 prep: bsq (exact numpy pairwise) + B-fragment tables ----------------
// B-frag layout (proven r6): Bhi[((CT*2+h)*64 + l)*8 + j] = bf16hi(emb[CT*16+(l&15)][(l>>4)*8+32*h+j])
__global__ void vq_prep(const float* __restrict__ emb, float* __restrict__ bsq,
                        unsigned short* __restrict__ Bhi, unsigned short* __restrict__ Blo) {
#pragma clang fp contract(off)
    int t = blockIdx.x * 256 + threadIdx.x;     // grid 128 -> 0..32767
    if (t < KCODES * DIM) {
        int c = t >> 6, d = t & 63;
        unsigned short h, s;
        bf16split(emb[t], h, s);
        int CT = c >> 4, col = c & 15, hh = d >> 5, j = d & 7, lh = (d >> 3) & 3;
        int addr = ((CT * 2 + hh) * 64 + (lh * 16 + col)) * 8 + j;
        Bhi[addr] = h;
        Blo[addr] = s;
    }
    if (t < KCODES) {
        const float* e = emb + (size_t)t * DIM;
        float r[8];
#pragma unroll
        for (int j = 0; j < 8; ++j) { float v = e[j]; r[j] = v * v; }
#pragma unroll
        for (int i = 8; i < 64; i += 8)
#pragma unroll
            for (int j = 0; j < 8; ++j) { float v = e[i + j]; r[j] = r[j] + v * v; }
        bsq[t] = ((r[0] + r[1]) + (r[2] + r[3])) + ((r[4] + r[5]) + (r[6] + r[7]));
    }
}

// ---------------- K2: MFMA distances, 128 rows/block; NT-store epilogue (enc/Q/idx) ----------------
__global__ __launch_bounds__(256) void vq_mfma(
    const float* __restrict__ x, const float* __restrict__ emb,
    const float* __restrict__ bsq,
    const unsigned short* __restrict__ Bhi, const unsigned short* __restrict__ Blo,
    int* __restrict__ counts, double* __restrict__ loss_acc, float* __restrict__ out,
    int* __restrict__ amb_count, int* __restrict__ amb_rows)
{
    __shared__ int    idx_l[128];
    __shared__ double wsum[4];

    const int tid  = threadIdx.x;
    const int l    = tid & 63;
    const int w    = tid >> 6;                 // wave 0..3
    const int row0 = blockIdx.x * 128;
    const int kb   = (l >> 4) * 8;             // lane k-offset
    const int rA   = row0 + w * 16 + (l & 15); // tile A row
    const int rB   = rA + 64;                  // tile B row

    // ---- A fragments for two row-tiles: global loads + register bf16 split ----
    sh8 ahf[2][2], alf[2][2];
#pragma unroll
    for (int t = 0; t < 2; ++t) {
        const float* xr = &x[(size_t)(t == 0 ? rA : rB) * 64 + kb];
        float4 a0 = *reinterpret_cast<const float4*>(xr);
        float4 a1 = *reinterpret_cast<const float4*>(xr + 4);
        float4 a2 = *reinterpret_cast<const float4*>(xr + 32);
        float4 a3 = *reinterpret_cast<const float4*>(xr + 36);
        float av[16] = {a0.x,a0.y,a0.z,a0.w, a1.x,a1.y,a1.z,a1.w,
                        a2.x,a2.y,a2.z,a2.w, a3.x,a3.y,a3.z,a3.w};
        unsigned short ah[16], al[16];
#pragma unroll
        for (int i = 0; i < 16; ++i) bf16split(av[i], ah[i], al[i]);
        ahf[t][0] = *reinterpret_cast<sh8*>(&ah[0]);
        ahf[t][1] = *reinterpret_cast<sh8*>(&ah[8]);
        alf[t][0] = *reinterpret_cast<sh8*>(&al[0]);
        alf[t][1] = *reinterpret_cast<sh8*>(&al[8]);
    }

    float m1[2][4], m2[2][4];
    int   i1[2][4];
#pragma unroll
    for (int t = 0; t < 2; ++t)
#pragma unroll
        for (int j = 0; j < 4; ++j) { m1[t][j] = 3.4e38f; m2[t][j] = 3.4e38f; i1[t][j] = 0; }

    const int col = l & 15;
#pragma unroll 2
    for (int CT = 0; CT < 32; ++CT) {
        sh8 bh0 = *reinterpret_cast<const sh8*>(&Bhi[(size_t)(CT * 2 + 0) * 512 + l * 8]);
        sh8 bh1 = *reinterpret_cast<const sh8*>(&Bhi[(size_t)(CT * 2 + 1) * 512 + l * 8]);
        sh8 bl0 = *reinterpret_cast<const sh8*>(&Blo[(size_t)(CT * 2 + 0) * 512 + l * 8]);
        sh8 bl1 = *reinterpret_cast<const sh8*>(&Blo[(size_t)(CT * 2 + 1) * 512 + l * 8]);
        int code = CT * 16 + col;
        float bs = bsq[code];
#pragma unroll
        for (int t = 0; t < 2; ++t) {
            f32x4 acc = {0.f, 0.f, 0.f, 0.f};
            acc = __builtin_amdgcn_mfma_f32_16x16x32_bf16(ahf[t][0], bh0, acc, 0, 0, 0);
            acc = __builtin_amdgcn_mfma_f32_16x16x32_bf16(ahf[t][1], bh1, acc, 0, 0, 0);
            acc = __builtin_amdgcn_mfma_f32_16x16x32_bf16(ahf[t][0], bl0, acc, 0, 0, 0);
            acc = __builtin_amdgcn_mfma_f32_16x16x32_bf16(ahf[t][1], bl1, acc, 0, 0, 0);
            acc = __builtin_amdgcn_mfma_f32_16x16x32_bf16(alf[t][0], bh0, acc, 0, 0, 0);
            acc = __builtin_amdgcn_mfma_f32_16x16x32_bf16(alf[t][1], bh1, acc, 0, 0, 0);
#pragma unroll
            for (int j = 0; j < 4; ++j) {
                float tt = bs - 2.0f * acc[j];     // ||x||^2 dropped: uniform per-row shift
                if (tt < m1[t][j]) { m2[t][j] = m1[t][j]; m1[t][j] = tt; i1[t][j] = code; }
                else if (tt < m2[t][j]) { m2[t][j] = tt; }
            }
        }
    }

    // ---- reduce (min, argmin, 2nd-min) across the 16 lanes sharing (l>>4) ----
#pragma unroll
    for (int off = 8; off >= 1; off >>= 1)
#pragma unroll
        for (int t = 0; t < 2; ++t)
#pragma unroll
            for (int j = 0; j < 4; ++j) {
                float ov1 = __shfl_xor(m1[t][j], off, 64);
                int   oi1 = __shfl_xor(i1[t][j], off, 64);
                float ov2 = __shfl_xor(m2[t][j], off, 64);
                float hi  = fmaxf(m1[t][j], ov1);
                m2[t][j] = fminf(fminf(m2[t][j], ov2), hi);
                if (ov1 < m1[t][j] || (ov1 == m1[t][j] && oi1 < i1[t][j])) { m1[t][j] = ov1; i1[t][j] = oi1; }
            }

    if ((l & 15) == 0) {
#pragma unroll
        for (int t = 0; t < 2; ++t)
#pragma unroll
            for (int j = 0; j < 4; ++j) {
                int r_loc = t * 64 + w * 16 + ((l >> 4) << 2) + j;   // D row = (lane>>4)*4 + reg
                int id = i1[t][j];
                idx_l[r_loc] = id;
                __builtin_nontemporal_store((float)id, &out[O_IDX + row0 + r_loc]);
                atomicAdd(&counts[id], 1);
                if (m2[t][j] - m1[t][j] <= AMB_WIN) {
                    int slot = atomicAdd(amb_count, 1);
                    if (slot < AMB_CAP) amb_rows[slot] = row0 + r_loc;
                }
            }
    }
    __syncthreads();

    // ---- one-hot tile: NT zero-fill (bypass LLC -> HBM stream), then NT ones ----
    // tile = 128 rows x 512 = 65536 floats at encp, encp is 8B- but not 16B-aligned
    {
        float* encp = out + O_ENC + (size_t)row0 * KCODES;
        if (tid < 2) {
            __builtin_nontemporal_store(0.f, &encp[tid]);           // lead 2
            __builtin_nontemporal_store(0.f, &encp[65534 + tid]);   // tail 2
        }
        f32x4* enc4 = reinterpret_cast<f32x4*>(encp + 2);
        f32x4 z = {0.f, 0.f, 0.f, 0.f};
        for (int i = tid; i < 16383; i += 256)
            __builtin_nontemporal_store(z, &enc4[i]);
        __syncthreads();   // zeros ordered before ones (block-scope fence)
        if (tid < 128)
            __builtin_nontemporal_store(1.0f, &encp[tid * 512 + idx_l[tid]]);
    }

    // ---- quantized_st + loss partial (NT scalar stores; x/emb reads stay cached) ----
    double lsum = 0.0;
#pragma unroll 4
    for (int k = 0; k < 32; ++k) {
        int i = tid + k * 256;               // 0..8191
        int r = i >> 6, d = i & 63;
        int id = idx_l[r];
        float xv = x[(size_t)(row0 + r) * 64 + d];
        float ev = emb[(size_t)id * 64 + d];
        float diff = ev - xv;
        __builtin_nontemporal_store(xv + diff, &out[O_Q + (size_t)(row0 + r) * 64 + d]);
        lsum += (double)diff * (double)diff;
    }

#pragma unroll
    for (int off = 32; off >= 1; off >>= 1) lsum += __shfl_xor(lsum, off, 64);
    if ((tid & 63) == 0) wsum[tid >> 6] = lsum;
    __syncthreads();
    if (tid == 0) atomicAdd(loss_acc, wsum[0] + wsum[1] + wsum[2] + wsum[3]);
}

// ---------------- K3: bit-exact np-replica recompute for ambiguous rows ----------------
__global__ __launch_bounds__(256, 2) void vq_fixup(
    const float* __restrict__ x, const float* __restrict__ emb,
    const float* __restrict__ bsq, int* __restrict__ counts,
    double* __restrict__ loss_acc, float* __restrict__ out,
    const int* __restrict__ amb_count, const int* __restrict__ amb_rows)
{
#pragma clang fp contract(off)
    __shared__ float Xt[64 * 34];     // Xt[d*34 + r], 32 rows
    __shared__ float Et[64 * 68];     // Et[d*68 + c], 64 codes/chunk
    __shared__ float sx_l[32];
    __shared__ int   rowid_l[32];

    const int tid = threadIdx.x;
    const int tx  = tid & 15;         // 4 codes each
    const int ty  = tid >> 4;         // 2 rows each
    int n = *amb_count; if (n > AMB_CAP) n = AMB_CAP;

    for (int base = blockIdx.x * 32; base < n; base += gridDim.x * 32) {
        const int nrows = min(32, n - base);
        if (tid < 32) {
            int e = base + tid;
            rowid_l[tid] = amb_rows[e < n ? e : (n - 1)];
        }
        __syncthreads();

#pragma unroll
        for (int k = 0; k < 8; ++k) {
            int i = tid + k * 256;    // 0..2047
            int r = i >> 6, d = i & 63;
            Xt[d * 34 + r] = x[(size_t)rowid_l[r] * 64 + d];
        }
        __syncthreads();

        if (tid < 32) {
            float rr[8];
#pragma unroll
            for (int j = 0; j < 8; ++j) { float v = Xt[j * 34 + tid]; rr[j] = v * v; }
#pragma unroll
            for (int i = 8; i < 64; i += 8)
#pragma unroll
                for (int j = 0; j < 8; ++j) { float v = Xt[(i + j) * 34 + tid]; rr[j] = rr[j] + v * v; }
            sx_l[tid] = ((rr[0] + rr[1]) + (rr[2] + rr[3])) + ((rr[4] + rr[5]) + (rr[6] + rr[7]));
        }
        __syncthreads();

        float b1[2]; int bi[2];
#pragma unroll
        for (int m = 0; m < 2; ++m) { b1[m] = 3.4e38f; bi[m] = 0; }

        for (int ch = 0; ch < 8; ++ch) {
            if (ch > 0) __syncthreads();
#pragma unroll
            for (int k = 0; k < 4; ++k) {
                int i = tid + k * 256;        // 0..1023 float4-units
                int c = i >> 4, c4 = i & 15;
                float4 v = *reinterpret_cast<const float4*>(&emb[(size_t)(ch * 64 + c) * 64 + c4 * 4]);
                Et[(c4 * 4 + 0) * 68 + c] = v.x;
                Et[(c4 * 4 + 1) * 68 + c] = v.y;
                Et[(c4 * 4 + 2) * 68 + c] = v.z;
                Et[(c4 * 4 + 3) * 68 + c] = v.w;
            }
            __syncthreads();

            float acc[2][4];
#pragma unroll
            for (int m = 0; m < 2; ++m)
#pragma unroll
                for (int nn = 0; nn < 4; ++nn) acc[m][nn] = 0.f;

#pragma unroll 8
            for (int d = 0; d < 64; ++d) {
                float2 a = *reinterpret_cast<const float2*>(&Xt[d * 34 + ty * 2]);
                float4 b = *reinterpret_cast<const float4*>(&Et[d * 68 + tx * 4]);
                float av[2] = {a.x, a.y};
                float bv[4] = {b.x, b.y, b.z, b.w};
#pragma unroll
                for (int m = 0; m < 2; ++m)
#pragma unroll
                    for (int nn = 0; nn < 4; ++nn)
                        acc[m][nn] = fmaf(av[m], bv[nn], acc[m][nn]);
            }

            const int cbase = ch * 64 + tx * 4;
            float4 bs4 = *reinterpret_cast<const float4*>(&bsq[cbase]);
            float bs[4] = {bs4.x, bs4.y, bs4.z, bs4.w};
#pragma unroll
            for (int m = 0; m < 2; ++m) {
                float sxm = sx_l[ty * 2 + m];
#pragma unroll
                for (int nn = 0; nn < 4; ++nn) {
                    float S  = sxm + bs[nn];
                    float dd = S - 2.0f * acc[m][nn];   // exact ref rounding
                    if (dd < b1[m]) { b1[m] = dd; bi[m] = cbase + nn; }
                }
            }
        }

#pragma unroll
        for (int off = 8; off >= 1; off >>= 1)
#pragma unroll
            for (int m = 0; m < 2; ++m) {
                float ov = __shfl_xor(b1[m], off, 64);
                int   oi = __shfl_xor(bi[m], off, 64);
                if (ov < b1[m] || (ov == b1[m] && oi < bi[m])) { b1[m] = ov; bi[m] = oi; }
            }

        if (tx == 0) {
#pragma unroll
            for (int m = 0; m < 2; ++m) {
                int rl = ty * 2 + m;
                if (rl < nrows) {
                    int row = rowid_l[rl];
                    int fi  = bi[m];
                    int old = (int)out[O_IDX + row];
                    if (fi != old) {
                        out[O_IDX + row] = (float)fi;
                        out[O_ENC + (size_t)row * KCODES + old] = 0.f;
                        out[O_ENC + (size_t)row * KCODES + fi]  = 1.f;
                        atomicAdd(&counts[old], -1);
                        atomicAdd(&counts[fi], 1);
                        double dl = 0.0;
                        for (int d = 0; d < 64; ++d) {
                            float xv   = Xt[d * 34 + rl];
                            float dn   = emb[(size_t)fi * 64 + d] - xv;
                            float dold = emb[(size_t)old * 64 + d] - xv;
                            out[O_Q + (size_t)row * 64 + d] = xv + dn;
                            dl += (double)dn * (double)dn - (double)dold * (double)dold;
                        }
                        atomicAdd(loss_acc, dl);
                    }
                }
            }
        }
        __syncthreads();
    }
}

// ---------------- K4 finalize: scalars ----------------
__global__ void vq_fin(const int* __restrict__ counts, const double* __restrict__ loss_acc,
                       float* __restrict__ out) {
    int t = threadIdx.x;     // 256
    double h = 0.0;
    for (int c = t; c < KCODES; c += 256) {
        double p = (double)counts[c] / (double)N_ROWS;
        h += p * log(p + 1e-10);
    }
#pragma unroll
    for (int off = 32; off >= 1; off >>= 1) h += __shfl_xor(h, off, 64);
    __shared__ double ws[4];
    if ((t & 63) == 0) ws[t >> 6] = h;
    __syncthreads();
    if (t == 0) {
        double H = ws[0] + ws[1] + ws[2] + ws[3];
        out[O_PERP] = (float)exp(-H);
        out[O_LOSS] = (float)(1.25 * (*loss_acc) / (double)(N_ROWS * DIM));
    }
}

extern "C" void kernel_launch(void* const* d_in, const int* in_sizes, int n_in,
                              void* d_out, int out_size, void* d_ws, size_t ws_size,
                              hipStream_t stream) {
    const float* x   = (const float*)d_in[0];
    const float* emb = (const float*)d_in[1];
    float* out = (float*)d_out;

    // ws: [0,2048) f32 bsq | [2048,4096) int counts | 4096 f64 loss | 4112 amb_count |
    //     [4160, 4160+4*AMB_CAP) amb_rows | 139264 Bhi (64KB) | 212992 Blo (64KB)
    float*          bsq       = (float*)d_ws;
    int*            counts    = (int*)((char*)d_ws + 2048);
    double*         loss_acc  = (double*)((char*)d_ws + 4096);
    int*            amb_count = (int*)((char*)d_ws + 4112);
    int*            amb_rows  = (int*)((char*)d_ws + 4160);
    unsigned short* Bhi       = (unsigned short*)((char*)d_ws + 139264);
    unsigned short* Blo       = (unsigned short*)((char*)d_ws + 212992);

    // Zero counts[512] + loss_acc + amb_count (bytes [2048, 4128)) -- tiny.
    (void)hipMemsetAsync((char*)d_ws + 2048, 0, 2080, stream);

    vq_prep<<<128, 256, 0, stream>>>(emb, bsq, Bhi, Blo);
    vq_mfma<<<N_ROWS / 128, 256, 0, stream>>>(x, emb, bsq, Bhi, Blo, counts, loss_acc, out,
                                              amb_count, amb_rows);
    vq_fixup<<<1024, 256, 0, stream>>>(x, emb, bsq, counts, loss_acc, out,
                                       amb_count, amb_rows);
    vq_fin<<<1, 256, 0, stream>>>(counts, loss_acc, out);
}

// Round 11
// 200.628 us; speedup vs baseline: 1.2093x; 1.1444x over previous
//
#include <hip/hip_runtime.h>
#include <math.h>

#define N_ROWS 131072
#define DIM 64
#define KCODES 512

// float-element offsets into d_out (concatenated outputs, all read back as f32)
#define O_LOSS 0
#define O_Q    1ull
#define O_PERP 8388609ull
#define O_ENC  8388610ull
#define O_IDX  75497474ull

// flip-possible window: ref-side grid/rounding <= ~3.1e-5 per pair, our MFMA-path
// delta <= ~2.2e-5 => true bound ~5.3e-5. 1.5e-4 gives 2.8x safety (~3.4/block).
#define AMB_WIN 1.5e-4f
#define AMB_CAP 64          // per-block; Poisson(3.4) beyond 64 ~ 1e-60

using sh8   = __attribute__((ext_vector_type(8))) short;
using f32x4 = __attribute__((ext_vector_type(4))) float;

__device__ __forceinline__ unsigned bf16rne_bits(float x) {
    unsigned u = __float_as_uint(x);
    return u + 0x7fffu + ((u >> 16) & 1u);
}
__device__ __forceinline__ void bf16split(float v, unsigned short& h, unsigned short& s) {
    unsigned hb = bf16rne_bits(v);
    float hf = __uint_as_float(hb & 0xffff0000u);
    unsigned lb = bf16rne_bits(v - hf);
    h = (unsigned short)(hb >> 16);
    s = (unsigned short)(lb >> 16);
}

// ---------------- K1 prep: bsq (exact numpy pairwise) + B-fragment tables + zeroing ----------------
// B-frag layout (proven r6): Bhi[((CT*2+h)*64 + l)*8 + j] = bf16hi(emb[CT*16+(l&15)][(l>>4)*8+32*h+j])
__global__ void vq_prep(const float* __restrict__ emb, float* __restrict__ bsq,
                        int* __restrict__ counts, double* __restrict__ loss_acc,
                        unsigned short* __restrict__ Bhi, unsigned short* __restrict__ Blo) {
#pragma clang fp contract(off)
    int t = blockIdx.x * 256 + threadIdx.x;     // grid 128 -> 0..32767
    if (t < KCODES * DIM) {
        int c = t >> 6, d = t & 63;
        unsigned short h, s;
        bf16split(emb[t], h, s);
        int CT = c >> 4, col = c & 15, hh = d >> 5, j = d & 7, lh = (d >> 3) & 3;
        int addr = ((CT * 2 + hh) * 64 + (lh * 16 + col)) * 8 + j;
        Bhi[addr] = h;
        Blo[addr] = s;
    }
    if (t < KCODES) {
        const float* e = emb + (size_t)t * DIM;
        float r[8];
#pragma unroll
        for (int j = 0; j < 8; ++j) { float v = e[j]; r[j] = v * v; }
#pragma unroll
        for (int i = 8; i < 64; i += 8)
#pragma unroll
            for (int j = 0; j < 8; ++j) { float v = e[i + j]; r[j] = r[j] + v * v; }
        bsq[t] = ((r[0] + r[1]) + (r[2] + r[3])) + ((r[4] + r[5]) + (r[6] + r[7]));
        counts[t] = 0;
    }
    if (t == 0) *loss_acc = 0.0;
}

// ---------------- K2: MFMA distances + in-block bit-exact resolve + all output writes ----------------
__global__ __launch_bounds__(256) void vq_mfma(
    const float* __restrict__ x, const float* __restrict__ emb,
    const float* __restrict__ bsq,
    const unsigned short* __restrict__ Bhi, const unsigned short* __restrict__ Blo,
    int* __restrict__ counts, double* __restrict__ loss_acc, float* __restrict__ out)
{
#pragma clang fp contract(off)
    __shared__ int    idx_l[128];
    __shared__ int    amb_list[AMB_CAP];
    __shared__ int    amb_n;
    __shared__ double wsum[4];

    const int tid  = threadIdx.x;
    const int l    = tid & 63;
    const int w    = tid >> 6;                 // wave 0..3
    const int row0 = blockIdx.x * 128;
    const int kb   = (l >> 4) * 8;             // lane k-offset
    const int rA   = row0 + w * 16 + (l & 15); // tile A row
    const int rB   = rA + 64;                  // tile B row

    if (tid == 0) amb_n = 0;

    // ---- A fragments for two row-tiles: global loads + register bf16 split ----
    sh8 ahf[2][2], alf[2][2];
#pragma unroll
    for (int t = 0; t < 2; ++t) {
        const float* xr = &x[(size_t)(t == 0 ? rA : rB) * 64 + kb];
        float4 a0 = *reinterpret_cast<const float4*>(xr);
        float4 a1 = *reinterpret_cast<const float4*>(xr + 4);
        float4 a2 = *reinterpret_cast<const float4*>(xr + 32);
        float4 a3 = *reinterpret_cast<const float4*>(xr + 36);
        float av[16] = {a0.x,a0.y,a0.z,a0.w, a1.x,a1.y,a1.z,a1.w,
                        a2.x,a2.y,a2.z,a2.w, a3.x,a3.y,a3.z,a3.w};
        unsigned short ah[16], al[16];
#pragma unroll
        for (int i = 0; i < 16; ++i) bf16split(av[i], ah[i], al[i]);
        ahf[t][0] = *reinterpret_cast<sh8*>(&ah[0]);
        ahf[t][1] = *reinterpret_cast<sh8*>(&ah[8]);
        alf[t][0] = *reinterpret_cast<sh8*>(&al[0]);
        alf[t][1] = *reinterpret_cast<sh8*>(&al[8]);
    }
    __syncthreads();   // amb_n = 0 visible to all waves

    float m1[2][4], m2[2][4];
    int   i1[2][4];
#pragma unroll
    for (int t = 0; t < 2; ++t)
#pragma unroll
        for (int j = 0; j < 4; ++j) { m1[t][j] = 3.4e38f; m2[t][j] = 3.4e38f; i1[t][j] = 0; }

    const int col = l & 15;
#pragma unroll 2
    for (int CT = 0; CT < 32; ++CT) {
        sh8 bh0 = *reinterpret_cast<const sh8*>(&Bhi[(size_t)(CT * 2 + 0) * 512 + l * 8]);
        sh8 bh1 = *reinterpret_cast<const sh8*>(&Bhi[(size_t)(CT * 2 + 1) * 512 + l * 8]);
        sh8 bl0 = *reinterpret_cast<const sh8*>(&Blo[(size_t)(CT * 2 + 0) * 512 + l * 8]);
        sh8 bl1 = *reinterpret_cast<const sh8*>(&Blo[(size_t)(CT * 2 + 1) * 512 + l * 8]);
        int code = CT * 16 + col;
        float bs = bsq[code];
#pragma unroll
        for (int t = 0; t < 2; ++t) {
            f32x4 acc = {0.f, 0.f, 0.f, 0.f};
            acc = __builtin_amdgcn_mfma_f32_16x16x32_bf16(ahf[t][0], bh0, acc, 0, 0, 0);
            acc = __builtin_amdgcn_mfma_f32_16x16x32_bf16(ahf[t][1], bh1, acc, 0, 0, 0);
            acc = __builtin_amdgcn_mfma_f32_16x16x32_bf16(ahf[t][0], bl0, acc, 0, 0, 0);
            acc = __builtin_amdgcn_mfma_f32_16x16x32_bf16(ahf[t][1], bl1, acc, 0, 0, 0);
            acc = __builtin_amdgcn_mfma_f32_16x16x32_bf16(alf[t][0], bh0, acc, 0, 0, 0);
            acc = __builtin_amdgcn_mfma_f32_16x16x32_bf16(alf[t][1], bh1, acc, 0, 0, 0);
#pragma unroll
            for (int j = 0; j < 4; ++j) {
                float tt = bs - 2.0f * acc[j];     // ||x||^2 dropped: uniform per-row shift
                if (tt < m1[t][j]) { m2[t][j] = m1[t][j]; m1[t][j] = tt; i1[t][j] = code; }
                else if (tt < m2[t][j]) { m2[t][j] = tt; }
            }
        }
    }

    // ---- reduce (min, argmin, 2nd-min) across the 16 lanes sharing (l>>4) ----
#pragma unroll
    for (int off = 8; off >= 1; off >>= 1)
#pragma unroll
        for (int t = 0; t < 2; ++t)
#pragma unroll
            for (int j = 0; j < 4; ++j) {
                float ov1 = __shfl_xor(m1[t][j], off, 64);
                int   oi1 = __shfl_xor(i1[t][j], off, 64);
                float ov2 = __shfl_xor(m2[t][j], off, 64);
                float hi  = fmaxf(m1[t][j], ov1);
                m2[t][j] = fminf(fminf(m2[t][j], ov2), hi);
                if (ov1 < m1[t][j] || (ov1 == m1[t][j] && oi1 < i1[t][j])) { m1[t][j] = ov1; i1[t][j] = oi1; }
            }

    if ((l & 15) == 0) {
#pragma unroll
        for (int t = 0; t < 2; ++t)
#pragma unroll
            for (int j = 0; j < 4; ++j) {
                int r_loc = t * 64 + w * 16 + ((l >> 4) << 2) + j;   // D row = (lane>>4)*4 + reg
                idx_l[r_loc] = i1[t][j];
                if (m2[t][j] - m1[t][j] <= AMB_WIN) {
                    int s = atomicAdd(&amb_n, 1);
                    if (s < AMB_CAP) amb_list[s] = r_loc;
                }
            }
    }
    __syncthreads();

    // ---- in-block bit-exact np-replica resolve for ambiguous rows (wave-parallel) ----
    {
        int na = amb_n < AMB_CAP ? amb_n : AMB_CAP;
        for (int e = w; e < na; e += 4) {
            int rl = amb_list[e];
            const float* xr = &x[(size_t)(row0 + rl) * 64];
            // exact ||x||^2, numpy 8-acc pairwise (squares rounded, no fma)
            float rr[8];
#pragma unroll
            for (int j = 0; j < 8; ++j) { float v = xr[j]; rr[j] = v * v; }
#pragma unroll
            for (int i = 8; i < 64; i += 8)
#pragma unroll
                for (int j = 0; j < 8; ++j) { float v = xr[i + j]; rr[j] = rr[j] + v * v; }
            float sx = ((rr[0] + rr[1]) + (rr[2] + rr[3])) + ((rr[4] + rr[5]) + (rr[6] + rr[7]));

            // 8 codes per lane, ascending: exact sequential FMA chain over d
            float best = 3.4e38f; int bidx = 0;
#pragma unroll
            for (int q = 0; q < 8; ++q) {
                int c = l * 8 + q;
                const float* ep = &emb[(size_t)c * 64];
                float acc = 0.f;
                for (int d = 0; d < 64; ++d) acc = fmaf(xr[d], ep[d], acc);
                float S  = sx + bsq[c];
                float dd = S - 2.0f * acc;           // exact ref rounding
                if (dd < best) { best = dd; bidx = c; }   // strict <: first occurrence
            }
#pragma unroll
            for (int off = 32; off >= 1; off >>= 1) {
                float ov = __shfl_xor(best, off, 64);
                int   oi = __shfl_xor(bidx, off, 64);
                if (ov < best || (ov == best && oi < bidx)) { best = ov; bidx = oi; }
            }
            if (l == 0) idx_l[rl] = bidx;
        }
    }
    __syncthreads();   // idx_l final for all 128 rows

    // ---- idx + counts ----
    if (tid < 128) {
        int id = idx_l[tid];
        out[O_IDX + row0 + tid] = (float)id;
        atomicAdd(&counts[id], 1);
    }

    // ---- quantized_st + loss partial ----
    double lsum = 0.0;
#pragma unroll 4
    for (int k = 0; k < 32; ++k) {
        int i = tid + k * 256;               // 0..8191
        int r = i >> 6, d = i & 63;
        int id = idx_l[r];
        float xv = x[(size_t)(row0 + r) * 64 + d];
        float ev = emb[(size_t)id * 64 + d];
        float diff = ev - xv;
        out[O_Q + (size_t)(row0 + r) * 64 + d] = xv + diff;
        lsum += (double)diff * (double)diff;
    }

    // ---- one-hot tile: dense zero fill, then scattered ones (r10-proven ordering) ----
    {
        float* encp = out + O_ENC + (size_t)row0 * KCODES;
        if (tid < 2) {
            encp[tid] = 0.f;                  // lead 2 (O_ENC % 4 == 2)
            encp[65534 + tid] = 0.f;          // tail 2
        }
        f32x4* enc4 = reinterpret_cast<f32x4*>(encp + 2);
        f32x4 z = {0.f, 0.f, 0.f, 0.f};
        for (int i = tid; i < 16383; i += 256) enc4[i] = z;
        __syncthreads();   // vmcnt(0) drain before barrier -> zeros ordered before ones
        if (tid < 128) encp[tid * 512 + idx_l[tid]] = 1.0f;
    }

    // ---- block-reduce loss, one f64 atomic per block ----
#pragma unroll
    for (int off = 32; off >= 1; off >>= 1) lsum += __shfl_xor(lsum, off, 64);
    if ((tid & 63) == 0) wsum[tid >> 6] = lsum;
    __syncthreads();
    if (tid == 0) atomicAdd(loss_acc, wsum[0] + wsum[1] + wsum[2] + wsum[3]);
}

// ---------------- K3 finalize: scalars ----------------
__global__ void vq_fin(const int* __restrict__ counts, const double* __restrict__ loss_acc,
                       float* __restrict__ out) {
    int t = threadIdx.x;     // 256
    double h = 0.0;
    for (int c = t; c < KCODES; c += 256) {
        double p = (double)counts[c] / (double)N_ROWS;
        h += p * log(p + 1e-10);
    }
#pragma unroll
    for (int off = 32; off >= 1; off >>= 1) h += __shfl_xor(h, off, 64);
    __shared__ double ws[4];
    if ((t & 63) == 0) ws[t >> 6] = h;
    __syncthreads();
    if (t == 0) {
        double H = ws[0] + ws[1] + ws[2] + ws[3];
        out[O_PERP] = (float)exp(-H);
        out[O_LOSS] = (float)(1.25 * (*loss_acc) / (double)(N_ROWS * DIM));
    }
}

extern "C" void kernel_launch(void* const* d_in, const int* in_sizes, int n_in,
                              void* d_out, int out_size, void* d_ws, size_t ws_size,
                              hipStream_t stream) {
    const float* x   = (const float*)d_in[0];
    const float* emb = (const float*)d_in[1];
    float* out = (float*)d_out;

    // ws: [0,2048) f32 bsq | [2048,4096) int counts | 4096 f64 loss |
    //     139264 Bhi (64KB) | 212992 Blo (64KB)
    float*          bsq      = (float*)d_ws;
    int*            counts   = (int*)((char*)d_ws + 2048);
    double*         loss_acc = (double*)((char*)d_ws + 4096);
    unsigned short* Bhi      = (unsigned short*)((char*)d_ws + 139264);
    unsigned short* Blo      = (unsigned short*)((char*)d_ws + 212992);

    vq_prep<<<128, 256, 0, stream>>>(emb, bsq, counts, loss_acc, Bhi, Blo);
    vq_mfma<<<N_ROWS / 128, 256, 0, stream>>>(x, emb, bsq, Bhi, Blo, counts, loss_acc, out);
    vq_fin<<<1, 256, 0, stream>>>(counts, loss_acc, out);
}